// Round 12
// baseline (386.368 us; speedup 1.0000x reference)
//
#include <hip/hip_runtime.h>
#include <stdint.h>

// ---------- types ----------
typedef __bf16 bf16_8 __attribute__((ext_vector_type(8)));
typedef __bf16 bf16_4 __attribute__((ext_vector_type(4)));
typedef float  f32x4  __attribute__((ext_vector_type(4)));

#define B_  1
#define S_  2048
#define D_  4096
#define H_  32
#define KV_ 8
#define HD_ 128

__device__ inline void gload_lds16(const void* g, void* l) {
  __builtin_amdgcn_global_load_lds((const __attribute__((address_space(1))) void*)g,
                                   (__attribute__((address_space(3))) void*)l, 16, 0, 0);
}

// ---------- fused fp32 -> bf16 convert (all 5 tensors; dst contiguous in ws) ----------
__global__ __launch_bounds__(256) void cvt_all(const float* __restrict__ x,
                                               const float* __restrict__ wq,
                                               const float* __restrict__ wk,
                                               const float* __restrict__ wv,
                                               const float* __restrict__ wo,
                                               __bf16* __restrict__ dst) {
  int i = blockIdx.x * 256 + threadIdx.x;  // float4-chunk index, total 12,582,912
  const float* s;
  int j = i;
  if (j < 2097152) s = x;
  else if ((j -= 2097152) < 4194304) s = wq;
  else if ((j -= 4194304) < 1048576) s = wk;
  else if ((j -= 1048576) < 1048576) s = wv;
  else { j -= 1048576; s = wo; }
  float4 v = ((const float4*)s)[j];
  bf16_4 o = { (__bf16)v.x, (__bf16)v.y, (__bf16)v.z, (__bf16)v.w };
  ((bf16_4*)dst)[i] = o;
}

// ---------- GEMM tile helpers: 128x128 tile, BK=64, XOR-swizzled LDS ----------
// LDS tile [128 rows][64 cols] = 16 KB per matrix, rows of 128 B = 8 chunks of 16 B.
// Physical chunk p of row r holds logical chunk p ^ (r&7). Staged via global_load_lds
// with pre-swizzled source (chunk (l&7)^(l>>3)); read side XORs ((row&7)<<4).
// Convention byte-identical to attn Vs staging (verified R7).
#define GSTAGE64(GBASE, LDSBASE)                                                   \
  _Pragma("unroll")                                                                \
  for (int u = 0; u < 4; ++u) {                                                    \
    int row_ = u * 32 + wv * 8 + (lane >> 3);                                      \
    int pc_ = (lane & 7) ^ (lane >> 3);                                            \
    gload_lds16((GBASE) + (size_t)row_ * D_ + k0 + pc_ * 8,                        \
                (LDSBASE) + (u * 32 + wv * 8) * 64);                               \
  }
#define FRAG64(LDSBASE, ROW, KS)                                                   \
  (*(const bf16_8*)((const char*)(LDSBASE) +                                       \
      (((ROW) * 128 + (KS) * 64 + (lane >> 4) * 16) ^ (((ROW) & 7) << 4))))

// ---------- fused QKV GEMM (128x128, BK=64, swizzled) + fused RoPE epilogue ----------
__global__ __launch_bounds__(256) void gemm_qkv(const __bf16* __restrict__ xb,
                                                const __bf16* __restrict__ wqb,
                                                const __bf16* __restrict__ wkb,
                                                const __bf16* __restrict__ wvb,
                                                const float* __restrict__ cosT,
                                                const float* __restrict__ sinT,
                                                __bf16* __restrict__ Qb,
                                                __bf16* __restrict__ Kb,
                                                __bf16* __restrict__ Vt) {
  __shared__ __bf16 As[128 * 64];
  __shared__ __bf16 Bs[128 * 64];
  const int nb = blockIdx.x, mb = blockIdx.y;
  const __bf16* W; int wrow0;
  if (nb < 32)      { W = wqb; wrow0 = nb * 128; }
  else if (nb < 40) { W = wkb; wrow0 = (nb - 32) * 128; }
  else              { W = wvb; wrow0 = (nb - 40) * 128; }
  const int tid = threadIdx.x, lane = tid & 63, wv = tid >> 6;
  const int wm = wv >> 1, wn = wv & 1;

  const __bf16* Ag = xb + (size_t)(mb * 128) * D_;
  const __bf16* Bg = W + (size_t)wrow0 * D_;

  const f32x4 zv = {0.f, 0.f, 0.f, 0.f};
  f32x4 acc[4][4];
#pragma unroll
  for (int i = 0; i < 4; ++i)
#pragma unroll
    for (int j = 0; j < 4; ++j) acc[i][j] = zv;

  for (int k0 = 0; k0 < D_; k0 += 64) {
    GSTAGE64(Ag, As);
    GSTAGE64(Bg, Bs);
    __syncthreads();
#pragma unroll
    for (int ks = 0; ks < 2; ++ks) {
      bf16_8 af[4], bfr[4];
#pragma unroll
      for (int i = 0; i < 4; ++i)
        af[i] = FRAG64(As, wm * 64 + i * 16 + (lane & 15), ks);
#pragma unroll
      for (int j = 0; j < 4; ++j)
        bfr[j] = FRAG64(Bs, wn * 64 + j * 16 + (lane & 15), ks);
#pragma unroll
      for (int i = 0; i < 4; ++i)
#pragma unroll
        for (int j = 0; j < 4; ++j)
          acc[i][j] = __builtin_amdgcn_mfma_f32_16x16x32_bf16(af[i], bfr[j], acc[i][j], 0, 0, 0);
    }
    __syncthreads();
  }

  // epilogue with fused RoPE for Q and K
#pragma unroll
  for (int i = 0; i < 4; ++i) {
    int row0 = mb * 128 + wm * 64 + i * 16 + (lane >> 4) * 4;
#pragma unroll
    for (int j = 0; j < 4; ++j) {
      int cl = wn * 64 + j * 16 + (lane & 15);
      if (nb < 40) {
        int f = cl >> 1;
        float sgn = (cl & 1) ? 1.f : -1.f;
        f32x4 v = acc[i][j];
        float o[4];
#pragma unroll
        for (int r = 0; r < 4; ++r) {
          float p = __shfl_xor(v[r], 1);  // partner column cl^1
          float c = cosT[(size_t)(row0 + r) * 64 + f];
          float s = sinT[(size_t)(row0 + r) * 64 + f];
          o[r] = v[r] * c + sgn * p * s;
        }
        if (nb < 32) {
          int colg = nb * 128 + cl;
#pragma unroll
          for (int r = 0; r < 4; ++r)
            Qb[(size_t)(row0 + r) * D_ + colg] = (__bf16)o[r];
        } else {
          int colg = (nb - 32) * 128 + cl;
#pragma unroll
          for (int r = 0; r < 4; ++r)
            Kb[(size_t)(row0 + r) * 1024 + colg] = (__bf16)o[r];
        }
      } else {
        int colg = (nb - 40) * 128 + cl;
        bf16_4 pv = { (__bf16)acc[i][j][0], (__bf16)acc[i][j][1],
                      (__bf16)acc[i][j][2], (__bf16)acc[i][j][3] };
        *(bf16_4*)&Vt[(size_t)colg * S_ + row0] = pv;  // transposed store
      }
    }
  }
}

// ---------- output-projection GEMM (128x128, BK=64, swizzled): out(fp32) = Ob @ wo^T ----------
__global__ __launch_bounds__(256) void gemm_out(const __bf16* __restrict__ Ob,
                                                const __bf16* __restrict__ wob,
                                                float* __restrict__ Of) {
  __shared__ __bf16 As[128 * 64];
  __shared__ __bf16 Bs[128 * 64];
  const int nb = blockIdx.x, mb = blockIdx.y;
  const int tid = threadIdx.x, lane = tid & 63, wv = tid >> 6;
  const int wm = wv >> 1, wn = wv & 1;

  const __bf16* Ag = Ob + (size_t)(mb * 128) * D_;
  const __bf16* Bg = wob + (size_t)(nb * 128) * D_;

  const f32x4 zv = {0.f, 0.f, 0.f, 0.f};
  f32x4 acc[4][4];
#pragma unroll
  for (int i = 0; i < 4; ++i)
#pragma unroll
    for (int j = 0; j < 4; ++j) acc[i][j] = zv;

  for (int k0 = 0; k0 < D_; k0 += 64) {
    GSTAGE64(Ag, As);
    GSTAGE64(Bg, Bs);
    __syncthreads();
#pragma unroll
    for (int ks = 0; ks < 2; ++ks) {
      bf16_8 af[4], bfr[4];
#pragma unroll
      for (int i = 0; i < 4; ++i)
        af[i] = FRAG64(As, wm * 64 + i * 16 + (lane & 15), ks);
#pragma unroll
      for (int j = 0; j < 4; ++j)
        bfr[j] = FRAG64(Bs, wn * 64 + j * 16 + (lane & 15), ks);
#pragma unroll
      for (int i = 0; i < 4; ++i)
#pragma unroll
        for (int j = 0; j < 4; ++j)
          acc[i][j] = __builtin_amdgcn_mfma_f32_16x16x32_bf16(af[i], bfr[j], acc[i][j], 0, 0, 0);
    }
    __syncthreads();
  }

#pragma unroll
  for (int i = 0; i < 4; ++i) {
    int row0 = mb * 128 + wm * 64 + i * 16 + (lane >> 4) * 4;
#pragma unroll
    for (int j = 0; j < 4; ++j) {
      int colg = nb * 128 + wn * 64 + j * 16 + (lane & 15);
#pragma unroll
      for (int r = 0; r < 4; ++r)
        Of[(size_t)(row0 + r) * D_ + colg] = acc[i][j][r];
    }
  }
}

// ---------- flash attention (causal, GQA), paired-triangle, SWAPPED QK^T, KVB=64 ----------
// 1-D grid of 512 blocks, XCD-aligned: kvh = blockIdx.x % 8 -> each XCD serves one KV head.
#define COMPUTE_TILE(ACC, MR, LR, AQ, QB0, DOMASK, KSB, VSB)                       \
  {                                                                                \
    f32x4 sfr_[4];                                                                 \
    __builtin_amdgcn_s_setprio(1);                                                 \
    _Pragma("unroll")                                                              \
    for (int nf = 0; nf < 4; ++nf) {                                               \
      f32x4 c_ = zv;                                                               \
      _Pragma("unroll")                                                            \
      for (int ks = 0; ks < 4; ++ks) {                                             \
        int n_ = nf * 16 + (lane & 15);                                            \
        int bo_ = (n_ * 256 + (ks * 32 + (lane >> 4) * 8) * 2) ^ ((n_ & 7) << 4);  \
        bf16_8 bk_ = *(const bf16_8*)((char*)(KSB) + bo_);                         \
        c_ = __builtin_amdgcn_mfma_f32_16x16x32_bf16(bk_, AQ[ks], c_, 0, 0, 0);    \
      }                                                                            \
      sfr_[nf] = c_;                                                               \
    }                                                                              \
    __builtin_amdgcn_s_setprio(0);                                                 \
    const int myq_ = (QB0) + w * 16 + (lane & 15);                                 \
    float pmn_[4];                                                                 \
    _Pragma("unroll")                                                              \
    for (int nf = 0; nf < 4; ++nf) {                                               \
      float t_ = -3e38f;                                                           \
      _Pragma("unroll")                                                            \
      for (int r = 0; r < 4; ++r) {                                                \
        int kcol_ = kb * 64 + nf * 16 + (lane >> 4) * 4 + r;                       \
        float v_ = sfr_[nf][r];                                                    \
        if ((DOMASK) && kcol_ > myq_) v_ = -1e9f;                                  \
        sfr_[nf][r] = v_;                                                          \
        t_ = fmaxf(t_, v_);                                                        \
      }                                                                            \
      pmn_[nf] = t_;                                                               \
    }                                                                              \
    float pm_ = fmaxf(fmaxf(pmn_[0], pmn_[1]), fmaxf(pmn_[2], pmn_[3]));           \
    pm_ = fmaxf(pm_, __shfl_xor(pm_, 16));                                         \
    pm_ = fmaxf(pm_, __shfl_xor(pm_, 32));                                         \
    if (!__all(pm_ <= MR + 8.f)) {                                                 \
      float mn_ = fmaxf(MR, pm_);                                                  \
      float rs_ = __expf(MR - mn_);                                                \
      MR = mn_;                                                                    \
      LR *= rs_;                                                                   \
      float rsb_[4];                                                               \
      _Pragma("unroll")                                                            \
      for (int r = 0; r < 4; ++r)                                                  \
        rsb_[r] = __shfl(rs_, (lane & 48) | ((lane >> 4) * 4 + r));                \
      _Pragma("unroll")                                                            \
      for (int d = 0; d < 8; ++d)                                                  \
        _Pragma("unroll")                                                          \
        for (int r = 0; r < 4; ++r) ACC[d][r] *= rsb_[r];                          \
    }                                                                              \
    float psn_[4];                                                                 \
    _Pragma("unroll")                                                              \
    for (int nf = 0; nf < 4; ++nf) {                                               \
      bf16_4 pk_;                                                                  \
      float t_ = 0.f;                                                              \
      _Pragma("unroll")                                                            \
      for (int r = 0; r < 4; ++r) {                                                \
        float p_ = __expf(sfr_[nf][r] - MR);                                       \
        t_ += p_;                                                                  \
        pk_[r] = (__bf16)p_;                                                       \
      }                                                                            \
      psn_[nf] = t_;                                                               \
      int bo_ = ((lane & 15) * 128 + nf * 32 + (lane >> 4) * 8) ^                  \
                (((lane & 15) & 7) << 4);                                          \
      *(bf16_4*)((char*)(&Ps[w][0]) + bo_) = pk_;                                  \
    }                                                                              \
    float ps_ = (psn_[0] + psn_[1]) + (psn_[2] + psn_[3]);                         \
    ps_ += __shfl_xor(ps_, 16);                                                    \
    ps_ += __shfl_xor(ps_, 32);                                                    \
    LR += ps_;                                                                     \
    bf16_8 ap_[2];                                                                 \
    _Pragma("unroll")                                                              \
    for (int ks = 0; ks < 2; ++ks) {                                               \
      int bo_ = ((lane & 15) * 128 + (ks * 32 + (lane >> 4) * 8) * 2) ^            \
                (((lane & 15) & 7) << 4);                                          \
      ap_[ks] = *(const bf16_8*)((char*)(&Ps[w][0]) + bo_);                        \
    }                                                                              \
    __builtin_amdgcn_s_setprio(1);                                                 \
    _Pragma("unroll")                                                              \
    for (int d = 0; d < 8; ++d) {                                                  \
      _Pragma("unroll")                                                            \
      for (int ks = 0; ks < 2; ++ks) {                                             \
        int dr_ = d * 16 + (lane & 15);                                            \
        int bo_ = (dr_ * 128 + (ks * 32 + (lane >> 4) * 8) * 2) ^ ((dr_ & 7) << 4);\
        bf16_8 bv_ = *(const bf16_8*)((char*)(VSB) + bo_);                         \
        ACC[d] = __builtin_amdgcn_mfma_f32_16x16x32_bf16(ap_[ks], bv_, ACC[d], 0, 0, 0); \
      }                                                                            \
    }                                                                              \
    __builtin_amdgcn_s_setprio(0);                                                 \
  }

__global__ __launch_bounds__(256) void attn_k(const __bf16* __restrict__ Qb,
                                              const __bf16* __restrict__ Kb,
                                              const __bf16* __restrict__ Vt,
                                              __bf16* __restrict__ Ob) {
  __shared__ __bf16 Ks[2][64 * 128];   // K[pos][d], row 256B, phys chunk c8 = logical c8^(row&7)
  __shared__ __bf16 Vs[2][128 * 64];   // V^T[d][pos], row 128B, same swizzle convention
  __shared__ __bf16 Ps[4][16 * 64];    // per-wave P[q][k], row 128B, swizzled
  const int bid = blockIdx.x;
  const int kvh = bid & 7;
  const int j   = bid >> 3;            // 0..63
  const int h   = kvh * 4 + (j & 3);
  const int x   = j >> 2;              // 0..15
  const int qlo = x, qhi = 31 - x;
  const int tid = threadIdx.x, lane = tid & 63, w = tid >> 6;

  const float sc = 0.08838834764831845f;  // 1/sqrt(128)

  bf16_8 aq0[4], aq1[4];
#pragma unroll
  for (int ks = 0; ks < 4; ++ks) {
    int rr = w * 16 + (lane & 15);
    int cc = h * 128 + ks * 32 + (lane >> 4) * 8;
    bf16_8 t0 = *(const bf16_8*)&Qb[(size_t)(qlo * 64 + rr) * D_ + cc];
    bf16_8 t1 = *(const bf16_8*)&Qb[(size_t)(qhi * 64 + rr) * D_ + cc];
#pragma unroll
    for (int e = 0; e < 8; ++e) {
      aq0[ks][e] = (__bf16)((float)t0[e] * sc);
      aq1[ks][e] = (__bf16)((float)t1[e] * sc);
    }
  }

  const f32x4 zv = {0.f, 0.f, 0.f, 0.f};
  f32x4 accO0[8], accO1[8];
#pragma unroll
  for (int d = 0; d < 8; ++d) { accO0[d] = zv; accO1[d] = zv; }
  float mr0 = -3e38f, lr0 = 0.f, mr1 = -3e38f, lr1 = 0.f;

#define KSTAGE(BUF, KB)                                                            \
  {                                                                                \
    _Pragma("unroll")                                                              \
    for (int u = 0; u < 4; ++u) {                                                  \
      int chunk = (u * 4 + w) * 64 + lane;                                         \
      int row = chunk >> 4, p8 = chunk & 15;                                       \
      gload_lds16(&Kb[(size_t)((KB) * 64 + row) * 1024 + kvh * 128 + (p8 ^ (row & 7)) * 8], \
                  &Ks[BUF][(u * 4 + w) * 512]);                                    \
    }                                                                              \
    _Pragma("unroll")                                                              \
    for (int u = 0; u < 4; ++u) {                                                  \
      int chunk = (u * 4 + w) * 64 + lane;                                         \
      int vr = chunk >> 3, p8 = chunk & 7;                                         \
      gload_lds16(&Vt[(size_t)(kvh * 128 + vr) * S_ + (KB) * 64 + (p8 ^ (vr & 7)) * 8], \
                  &Vs[BUF][(u * 4 + w) * 512]);                                    \
    }                                                                              \
  }

  KSTAGE(0, 0);
  asm volatile("s_waitcnt vmcnt(0)" ::: "memory");
  __syncthreads();

  for (int kb = 0; kb <= qhi; ++kb) {
    const int cur = kb & 1;
    if (kb < qhi) KSTAGE(cur ^ 1, kb + 1);  // async into idle buffer
    const __bf16* ksb = &Ks[cur][0];
    const __bf16* vsb = &Vs[cur][0];
    COMPUTE_TILE(accO1, mr1, lr1, aq1, qhi * 64, (kb == qhi), ksb, vsb);
    if (kb <= qlo) COMPUTE_TILE(accO0, mr0, lr0, aq0, qlo * 64, (kb == qlo), ksb, vsb);
    if (kb < qhi) {
      asm volatile("s_waitcnt vmcnt(0)" ::: "memory");
      __syncthreads();
    }
  }

  float inv0[4], inv1[4];
#pragma unroll
  for (int r = 0; r < 4; ++r) {
    int src = (lane & 48) | ((lane >> 4) * 4 + r);
    inv0[r] = 1.0f / __shfl(lr0, src);
    inv1[r] = 1.0f / __shfl(lr1, src);
  }
#pragma unroll
  for (int d = 0; d < 8; ++d) {
#pragma unroll
    for (int r = 0; r < 4; ++r) {
      size_t rl = (size_t)(qlo * 64 + w * 16 + (lane >> 4) * 4 + r);
      size_t rh = (size_t)(qhi * 64 + w * 16 + (lane >> 4) * 4 + r);
      int cc = h * 128 + d * 16 + (lane & 15);
      Ob[rl * D_ + cc] = (__bf16)(accO0[d][r] * inv0[r]);
      Ob[rh * D_ + cc] = (__bf16)(accO1[d][r] * inv1[r]);
    }
  }
}

// ---------- launch ----------
extern "C" void kernel_launch(void* const* d_in, const int* in_sizes, int n_in,
                              void* d_out, int out_size, void* d_ws, size_t ws_size,
                              hipStream_t stream) {
  const float* x    = (const float*)d_in[0];
  const float* wq   = (const float*)d_in[1];
  const float* wk   = (const float*)d_in[2];
  const float* wv   = (const float*)d_in[3];
  const float* wo   = (const float*)d_in[4];
  const float* cosT = (const float*)d_in[5];
  const float* sinT = (const float*)d_in[6];
  float* out = (float*)d_out;
  char* ws = (char*)d_ws;

  __bf16* xb  = (__bf16*)(ws + 0);            // 2048x4096; later reused as Ob
  __bf16* wqb = (__bf16*)(ws + 16777216);     // 4096x4096
  __bf16* wkb = (__bf16*)(ws + 50331648);     // 1024x4096
  __bf16* wvb = (__bf16*)(ws + 58720256);     // 1024x4096
  __bf16* wob = (__bf16*)(ws + 67108864);     // 4096x4096
  __bf16* Qb  = (__bf16*)(ws + 100663296);    // 2048x4096
  __bf16* Kb  = (__bf16*)(ws + 117440512);    // 2048x1024
  __bf16* Vt  = (__bf16*)(ws + 121634816);    // 1024x2048 (V transposed)
  __bf16* Ob  = xb;                           // alias: x consumed before attention writes

  // fused fp32 -> bf16 (dst = xb..wob contiguous)
  cvt_all<<<49152, 256, 0, stream>>>(x, wq, wk, wv, wo, xb);

  // fused QKV projection + RoPE (BK=64, swizzled LDS; V stored transposed)
  gemm_qkv<<<dim3(48, 16), 256, 0, stream>>>(xb, wqb, wkb, wvb, cosT, sinT, Qb, Kb, Vt);

  // causal GQA flash attention (paired triangle, swapped QK^T, XCD-aligned KV heads)
  attn_k<<<512, 256, 0, stream>>>(Qb, Kb, Vt, Ob);

  // output projection -> fp32 (BK=64, swizzled LDS)
  gemm_out<<<dim3(32, 16), 256, 0, stream>>>(Ob, wob, out);
}

// Round 13
// 372.483 us; speedup vs baseline: 1.0373x; 1.0373x over previous
//
#include <hip/hip_runtime.h>
#include <stdint.h>

// ---------- types ----------
typedef __bf16 bf16_8 __attribute__((ext_vector_type(8)));
typedef __bf16 bf16_4 __attribute__((ext_vector_type(4)));
typedef float  f32x4  __attribute__((ext_vector_type(4)));

#define B_  1
#define S_  2048
#define D_  4096
#define H_  32
#define KV_ 8
#define HD_ 128

__device__ inline void gload_lds16(const void* g, void* l) {
  __builtin_amdgcn_global_load_lds((const __attribute__((address_space(1))) void*)g,
                                   (__attribute__((address_space(3))) void*)l, 16, 0, 0);
}

// ---------- fused fp32 -> bf16 convert (all 5 tensors; dst contiguous in ws) ----------
__global__ __launch_bounds__(256) void cvt_all(const float* __restrict__ x,
                                               const float* __restrict__ wq,
                                               const float* __restrict__ wk,
                                               const float* __restrict__ wv,
                                               const float* __restrict__ wo,
                                               __bf16* __restrict__ dst) {
  int i = blockIdx.x * 256 + threadIdx.x;  // float4-chunk index, total 12,582,912
  const float* s;
  int j = i;
  if (j < 2097152) s = x;
  else if ((j -= 2097152) < 4194304) s = wq;
  else if ((j -= 4194304) < 1048576) s = wk;
  else if ((j -= 1048576) < 1048576) s = wv;
  else { j -= 1048576; s = wo; }
  float4 v = ((const float4*)s)[j];
  bf16_4 o = { (__bf16)v.x, (__bf16)v.y, (__bf16)v.z, (__bf16)v.w };
  ((bf16_4*)dst)[i] = o;
}

// ---------- fused QKV GEMM (m97 128x128, BK=32) + fused RoPE epilogue ----------
__global__ __launch_bounds__(256) void gemm_qkv(const __bf16* __restrict__ xb,
                                                const __bf16* __restrict__ wqb,
                                                const __bf16* __restrict__ wkb,
                                                const __bf16* __restrict__ wvb,
                                                const float* __restrict__ cosT,
                                                const float* __restrict__ sinT,
                                                __bf16* __restrict__ Qb,
                                                __bf16* __restrict__ Kb,
                                                __bf16* __restrict__ Vt) {
  __shared__ __bf16 As[128 * 32];
  __shared__ __bf16 Bs[128 * 32];
  const int nb = blockIdx.x, mb = blockIdx.y;
  const __bf16* W; int wrow0;
  if (nb < 32)      { W = wqb; wrow0 = nb * 128; }
  else if (nb < 40) { W = wkb; wrow0 = (nb - 32) * 128; }
  else              { W = wvb; wrow0 = (nb - 40) * 128; }
  const int tid = threadIdx.x, lane = tid & 63, wv = tid >> 6;
  const int wm = wv >> 1, wn = wv & 1;
  const int srow = lane >> 2, scol = (lane & 3) * 8;

  const __bf16* Ag0 = xb + (size_t)(mb * 128 + 2 * wv * 16 + srow) * D_ + scol;
  const __bf16* Bg0 = W  + (size_t)(wrow0 + 2 * wv * 16 + srow) * D_ + scol;
  __bf16* Al = As + 2 * wv * 512;
  __bf16* Bl = Bs + 2 * wv * 512;

  const f32x4 zv = {0.f, 0.f, 0.f, 0.f};
  f32x4 acc[4][4];
#pragma unroll
  for (int i = 0; i < 4; ++i)
#pragma unroll
    for (int j = 0; j < 4; ++j) acc[i][j] = zv;

  for (int k0 = 0; k0 < D_; k0 += 32) {
    gload_lds16(Ag0 + k0, Al);
    gload_lds16(Ag0 + (size_t)16 * D_ + k0, Al + 512);
    gload_lds16(Bg0 + k0, Bl);
    gload_lds16(Bg0 + (size_t)16 * D_ + k0, Bl + 512);
    __syncthreads();
    bf16_8 af[4], bfr[4];
#pragma unroll
    for (int i = 0; i < 4; ++i)
      af[i] = *(const bf16_8*)&As[(wm * 64 + i * 16 + (lane & 15)) * 32 + (lane >> 4) * 8];
#pragma unroll
    for (int j = 0; j < 4; ++j)
      bfr[j] = *(const bf16_8*)&Bs[(wn * 64 + j * 16 + (lane & 15)) * 32 + (lane >> 4) * 8];
#pragma unroll
    for (int i = 0; i < 4; ++i)
#pragma unroll
      for (int j = 0; j < 4; ++j)
        acc[i][j] = __builtin_amdgcn_mfma_f32_16x16x32_bf16(af[i], bfr[j], acc[i][j], 0, 0, 0);
    __syncthreads();
  }

  // epilogue with fused RoPE for Q and K
#pragma unroll
  for (int i = 0; i < 4; ++i) {
    int row0 = mb * 128 + wm * 64 + i * 16 + (lane >> 4) * 4;
#pragma unroll
    for (int j = 0; j < 4; ++j) {
      int cl = wn * 64 + j * 16 + (lane & 15);
      if (nb < 40) {
        int f = cl >> 1;
        float sgn = (cl & 1) ? 1.f : -1.f;
        f32x4 v = acc[i][j];
        float o[4];
#pragma unroll
        for (int r = 0; r < 4; ++r) {
          float p = __shfl_xor(v[r], 1);  // partner column cl^1
          float c = cosT[(size_t)(row0 + r) * 64 + f];
          float s = sinT[(size_t)(row0 + r) * 64 + f];
          o[r] = v[r] * c + sgn * p * s;
        }
        if (nb < 32) {
          int colg = nb * 128 + cl;
#pragma unroll
          for (int r = 0; r < 4; ++r)
            Qb[(size_t)(row0 + r) * D_ + colg] = (__bf16)o[r];
        } else {
          int colg = (nb - 32) * 128 + cl;
#pragma unroll
          for (int r = 0; r < 4; ++r)
            Kb[(size_t)(row0 + r) * 1024 + colg] = (__bf16)o[r];
        }
      } else {
        int colg = (nb - 40) * 128 + cl;
        bf16_4 pv = { (__bf16)acc[i][j][0], (__bf16)acc[i][j][1],
                      (__bf16)acc[i][j][2], (__bf16)acc[i][j][3] };
        *(bf16_4*)&Vt[(size_t)colg * S_ + row0] = pv;  // transposed store
      }
    }
  }
}

// ---------- output-projection GEMM: out(fp32) = Ob @ wo^T (m97 128x128) ----------
__global__ __launch_bounds__(256) void gemm_out(const __bf16* __restrict__ Ob,
                                                const __bf16* __restrict__ wob,
                                                float* __restrict__ Of) {
  __shared__ __bf16 As[128 * 32];
  __shared__ __bf16 Bs[128 * 32];
  const int nb = blockIdx.x, mb = blockIdx.y;
  const int tid = threadIdx.x, lane = tid & 63, wv = tid >> 6;
  const int wm = wv >> 1, wn = wv & 1;
  const int srow = lane >> 2, scol = (lane & 3) * 8;

  const __bf16* Ag0 = Ob  + (size_t)(mb * 128 + 2 * wv * 16 + srow) * D_ + scol;
  const __bf16* Bg0 = wob + (size_t)(nb * 128 + 2 * wv * 16 + srow) * D_ + scol;
  __bf16* Al = As + 2 * wv * 512;
  __bf16* Bl = Bs + 2 * wv * 512;

  const f32x4 zv = {0.f, 0.f, 0.f, 0.f};
  f32x4 acc[4][4];
#pragma unroll
  for (int i = 0; i < 4; ++i)
#pragma unroll
    for (int j = 0; j < 4; ++j) acc[i][j] = zv;

  for (int k0 = 0; k0 < D_; k0 += 32) {
    gload_lds16(Ag0 + k0, Al);
    gload_lds16(Ag0 + (size_t)16 * D_ + k0, Al + 512);
    gload_lds16(Bg0 + k0, Bl);
    gload_lds16(Bg0 + (size_t)16 * D_ + k0, Bl + 512);
    __syncthreads();
    bf16_8 af[4], bfr[4];
#pragma unroll
    for (int i = 0; i < 4; ++i)
      af[i] = *(const bf16_8*)&As[(wm * 64 + i * 16 + (lane & 15)) * 32 + (lane >> 4) * 8];
#pragma unroll
    for (int j = 0; j < 4; ++j)
      bfr[j] = *(const bf16_8*)&Bs[(wn * 64 + j * 16 + (lane & 15)) * 32 + (lane >> 4) * 8];
#pragma unroll
    for (int i = 0; i < 4; ++i)
#pragma unroll
      for (int j = 0; j < 4; ++j)
        acc[i][j] = __builtin_amdgcn_mfma_f32_16x16x32_bf16(af[i], bfr[j], acc[i][j], 0, 0, 0);
    __syncthreads();
  }

#pragma unroll
  for (int i = 0; i < 4; ++i) {
    int row0 = mb * 128 + wm * 64 + i * 16 + (lane >> 4) * 4;
#pragma unroll
    for (int j = 0; j < 4; ++j) {
      int colg = nb * 128 + wn * 64 + j * 16 + (lane & 15);
#pragma unroll
      for (int r = 0; r < 4; ++r)
        Of[(size_t)(row0 + r) * D_ + colg] = acc[i][j][r];
    }
  }
}

// ---------- flash attention (causal, GQA), parallel-pair, SWAPPED QK^T, KVB=64 ----------
// 512 blocks (XCD-aligned kvh = bid%8), 512 threads = 8 waves: waves 0-3 -> hi tile,
// waves 4-7 -> lo tile. Shared K/V staging serves both (lo KV range subset of hi).
// Fragment math byte-identical to R11; Ps indexed by wid (8 slots).
#define COMPUTE_TILE(ACC, MR, LR, AQ, QB0, DOMASK, KSB, VSB)                       \
  {                                                                                \
    f32x4 sfr_[4];                                                                 \
    __builtin_amdgcn_s_setprio(1);                                                 \
    _Pragma("unroll")                                                              \
    for (int nf = 0; nf < 4; ++nf) {                                               \
      f32x4 c_ = zv;                                                               \
      _Pragma("unroll")                                                            \
      for (int ks = 0; ks < 4; ++ks) {                                             \
        int n_ = nf * 16 + (lane & 15);                                            \
        int bo_ = (n_ * 256 + (ks * 32 + (lane >> 4) * 8) * 2) ^ ((n_ & 7) << 4);  \
        bf16_8 bk_ = *(const bf16_8*)((char*)(KSB) + bo_);                         \
        c_ = __builtin_amdgcn_mfma_f32_16x16x32_bf16(bk_, AQ[ks], c_, 0, 0, 0);    \
      }                                                                            \
      sfr_[nf] = c_;                                                               \
    }                                                                              \
    __builtin_amdgcn_s_setprio(0);                                                 \
    const int myq_ = (QB0) + w4 * 16 + (lane & 15);                                \
    float pmn_[4];                                                                 \
    _Pragma("unroll")                                                              \
    for (int nf = 0; nf < 4; ++nf) {                                               \
      float t_ = -3e38f;                                                           \
      _Pragma("unroll")                                                            \
      for (int r = 0; r < 4; ++r) {                                                \
        int kcol_ = kb * 64 + nf * 16 + (lane >> 4) * 4 + r;                       \
        float v_ = sfr_[nf][r];                                                    \
        if ((DOMASK) && kcol_ > myq_) v_ = -1e9f;                                  \
        sfr_[nf][r] = v_;                                                          \
        t_ = fmaxf(t_, v_);                                                        \
      }                                                                            \
      pmn_[nf] = t_;                                                               \
    }                                                                              \
    float pm_ = fmaxf(fmaxf(pmn_[0], pmn_[1]), fmaxf(pmn_[2], pmn_[3]));           \
    pm_ = fmaxf(pm_, __shfl_xor(pm_, 16));                                         \
    pm_ = fmaxf(pm_, __shfl_xor(pm_, 32));                                         \
    if (!__all(pm_ <= MR + 8.f)) {                                                 \
      float mn_ = fmaxf(MR, pm_);                                                  \
      float rs_ = __expf(MR - mn_);                                                \
      MR = mn_;                                                                    \
      LR *= rs_;                                                                   \
      float rsb_[4];                                                               \
      _Pragma("unroll")                                                            \
      for (int r = 0; r < 4; ++r)                                                  \
        rsb_[r] = __shfl(rs_, (lane & 48) | ((lane >> 4) * 4 + r));                \
      _Pragma("unroll")                                                            \
      for (int d = 0; d < 8; ++d)                                                  \
        _Pragma("unroll")                                                          \
        for (int r = 0; r < 4; ++r) ACC[d][r] *= rsb_[r];                          \
    }                                                                              \
    float psn_[4];                                                                 \
    _Pragma("unroll")                                                              \
    for (int nf = 0; nf < 4; ++nf) {                                               \
      bf16_4 pk_;                                                                  \
      float t_ = 0.f;                                                              \
      _Pragma("unroll")                                                            \
      for (int r = 0; r < 4; ++r) {                                                \
        float p_ = __expf(sfr_[nf][r] - MR);                                       \
        t_ += p_;                                                                  \
        pk_[r] = (__bf16)p_;                                                       \
      }                                                                            \
      psn_[nf] = t_;                                                               \
      int bo_ = ((lane & 15) * 128 + nf * 32 + (lane >> 4) * 8) ^                  \
                (((lane & 15) & 7) << 4);                                          \
      *(bf16_4*)((char*)(&Ps[wid][0]) + bo_) = pk_;                                \
    }                                                                              \
    float ps_ = (psn_[0] + psn_[1]) + (psn_[2] + psn_[3]);                         \
    ps_ += __shfl_xor(ps_, 16);                                                    \
    ps_ += __shfl_xor(ps_, 32);                                                    \
    LR += ps_;                                                                     \
    bf16_8 ap_[2];                                                                 \
    _Pragma("unroll")                                                              \
    for (int ks = 0; ks < 2; ++ks) {                                               \
      int bo_ = ((lane & 15) * 128 + (ks * 32 + (lane >> 4) * 8) * 2) ^            \
                (((lane & 15) & 7) << 4);                                          \
      ap_[ks] = *(const bf16_8*)((char*)(&Ps[wid][0]) + bo_);                      \
    }                                                                              \
    __builtin_amdgcn_s_setprio(1);                                                 \
    _Pragma("unroll")                                                              \
    for (int d = 0; d < 8; ++d) {                                                  \
      _Pragma("unroll")                                                            \
      for (int ks = 0; ks < 2; ++ks) {                                             \
        int dr_ = d * 16 + (lane & 15);                                            \
        int bo_ = (dr_ * 128 + (ks * 32 + (lane >> 4) * 8) * 2) ^ ((dr_ & 7) << 4);\
        bf16_8 bv_ = *(const bf16_8*)((char*)(VSB) + bo_);                         \
        ACC[d] = __builtin_amdgcn_mfma_f32_16x16x32_bf16(ap_[ks], bv_, ACC[d], 0, 0, 0); \
      }                                                                            \
    }                                                                              \
    __builtin_amdgcn_s_setprio(0);                                                 \
  }

__global__ __launch_bounds__(512, 4) void attn_k(const __bf16* __restrict__ Qb,
                                                 const __bf16* __restrict__ Kb,
                                                 const __bf16* __restrict__ Vt,
                                                 __bf16* __restrict__ Ob) {
  __shared__ __bf16 Ks[2][64 * 128];   // K[pos][d], row 256B, phys chunk = logical^(row&7)
  __shared__ __bf16 Vs[2][128 * 64];   // V^T[d][pos], row 128B, same swizzle convention
  __shared__ __bf16 Ps[8][16 * 64];    // per-wave P[q][k], row 128B, swizzled
  const int bid = blockIdx.x;
  const int kvh = bid & 7;             // XCD-aligned: each XCD serves one KV head
  const int j   = bid >> 3;            // 0..63
  const int h   = kvh * 4 + (j & 3);
  const int x   = j >> 2;              // 0..15
  const int qlo = x, qhi = 31 - x;
  const int tid = threadIdx.x, lane = tid & 63, wid = tid >> 6;
  const int w4 = wid & 3;              // row-group within tile
  const int qt = (wid < 4) ? qhi : qlo;  // waves 0-3: hi tile, 4-7: lo tile

  const float sc = 0.08838834764831845f;  // 1/sqrt(128)

  // Q fragments for this wave's tile, pre-scaled by 1/sqrt(d)
  bf16_8 aq[4];
#pragma unroll
  for (int ks = 0; ks < 4; ++ks) {
    int rr = qt * 64 + w4 * 16 + (lane & 15);
    int cc = h * 128 + ks * 32 + (lane >> 4) * 8;
    bf16_8 t = *(const bf16_8*)&Qb[(size_t)rr * D_ + cc];
#pragma unroll
    for (int e = 0; e < 8; ++e) aq[ks][e] = (__bf16)((float)t[e] * sc);
  }

  const f32x4 zv = {0.f, 0.f, 0.f, 0.f};
  f32x4 acc[8];
#pragma unroll
  for (int d = 0; d < 8; ++d) acc[d] = zv;
  float mr = -3e38f, lr = 0.f;

  // 1024 K-chunks + 1024 V-chunks over 512 threads: 2+2 gload_lds16 each.
#define KSTAGE(BUF, KB)                                                            \
  {                                                                                \
    _Pragma("unroll")                                                              \
    for (int u = 0; u < 2; ++u) {                                                  \
      int chunk = (u * 8 + wid) * 64 + lane;                                       \
      int row = chunk >> 4, p8 = chunk & 15;                                       \
      gload_lds16(&Kb[(size_t)((KB) * 64 + row) * 1024 + kvh * 128 + (p8 ^ (row & 7)) * 8], \
                  &Ks[BUF][(u * 8 + wid) * 512]);                                  \
    }                                                                              \
    _Pragma("unroll")                                                              \
    for (int u = 0; u < 2; ++u) {                                                  \
      int chunk = (u * 8 + wid) * 64 + lane;                                       \
      int vr = chunk >> 3, p8 = chunk & 7;                                         \
      gload_lds16(&Vt[(size_t)(kvh * 128 + vr) * S_ + (KB) * 64 + (p8 ^ (vr & 7)) * 8], \
                  &Vs[BUF][(u * 8 + wid) * 512]);                                  \
    }                                                                              \
  }

  KSTAGE(0, 0);
  asm volatile("s_waitcnt vmcnt(0)" ::: "memory");
  __syncthreads();

  for (int kb = 0; kb <= qhi; ++kb) {
    const int cur = kb & 1;
    if (kb < qhi) KSTAGE(cur ^ 1, kb + 1);  // async into idle buffer
    const __bf16* ksb = &Ks[cur][0];
    const __bf16* vsb = &Vs[cur][0];
    if (kb <= qt) COMPUTE_TILE(acc, mr, lr, aq, qt * 64, (kb == qt), ksb, vsb);
    if (kb < qhi) {
      asm volatile("s_waitcnt vmcnt(0)" ::: "memory");
      __syncthreads();
    }
  }

  // normalize + store (l lives at lane q = lane&15 -> shuffle per row)
  float inv[4];
#pragma unroll
  for (int r = 0; r < 4; ++r)
    inv[r] = 1.0f / __shfl(lr, (lane & 48) | ((lane >> 4) * 4 + r));
#pragma unroll
  for (int d = 0; d < 8; ++d) {
#pragma unroll
    for (int r = 0; r < 4; ++r) {
      size_t row = (size_t)(qt * 64 + w4 * 16 + (lane >> 4) * 4 + r);
      Ob[row * D_ + h * 128 + d * 16 + (lane & 15)] = (__bf16)(acc[d][r] * inv[r]);
    }
  }
}

// ---------- launch ----------
extern "C" void kernel_launch(void* const* d_in, const int* in_sizes, int n_in,
                              void* d_out, int out_size, void* d_ws, size_t ws_size,
                              hipStream_t stream) {
  const float* x    = (const float*)d_in[0];
  const float* wq   = (const float*)d_in[1];
  const float* wk   = (const float*)d_in[2];
  const float* wv   = (const float*)d_in[3];
  const float* wo   = (const float*)d_in[4];
  const float* cosT = (const float*)d_in[5];
  const float* sinT = (const float*)d_in[6];
  float* out = (float*)d_out;
  char* ws = (char*)d_ws;

  __bf16* xb  = (__bf16*)(ws + 0);            // 2048x4096; later reused as Ob
  __bf16* wqb = (__bf16*)(ws + 16777216);     // 4096x4096
  __bf16* wkb = (__bf16*)(ws + 50331648);     // 1024x4096
  __bf16* wvb = (__bf16*)(ws + 58720256);     // 1024x4096
  __bf16* wob = (__bf16*)(ws + 67108864);     // 4096x4096
  __bf16* Qb  = (__bf16*)(ws + 100663296);    // 2048x4096
  __bf16* Kb  = (__bf16*)(ws + 117440512);    // 2048x1024
  __bf16* Vt  = (__bf16*)(ws + 121634816);    // 1024x2048 (V transposed)
  __bf16* Ob  = xb;                           // alias: x consumed before attention writes

  // fused fp32 -> bf16 (dst = xb..wob contiguous)
  cvt_all<<<49152, 256, 0, stream>>>(x, wq, wk, wv, wo, xb);

  // fused QKV projection + RoPE, m97 128x128 BK=32 (V stored transposed)
  gemm_qkv<<<dim3(48, 16), 256, 0, stream>>>(xb, wqb, wkb, wvb, cosT, sinT, Qb, Kb, Vt);

  // causal GQA flash attention (parallel-pair, swapped QK^T, XCD-aligned KV heads)
  attn_k<<<512, 512, 0, stream>>>(Qb, Kb, Vt, Ob);

  // output projection -> fp32 (m97 128x128 BK=32)
  gemm_out<<<dim3(32, 16), 256, 0, stream>>>(Ob, wob, out);
}

// Round 14
// 353.138 us; speedup vs baseline: 1.0941x; 1.0548x over previous
//
#include <hip/hip_runtime.h>
#include <stdint.h>

// ---------- types ----------
typedef __bf16 bf16_8 __attribute__((ext_vector_type(8)));
typedef __bf16 bf16_4 __attribute__((ext_vector_type(4)));
typedef float  f32x4  __attribute__((ext_vector_type(4)));

#define B_  1
#define S_  2048
#define D_  4096
#define H_  32
#define KV_ 8
#define HD_ 128

__device__ inline void gload_lds16(const void* g, void* l) {
  __builtin_amdgcn_global_load_lds((const __attribute__((address_space(1))) void*)g,
                                   (__attribute__((address_space(3))) void*)l, 16, 0, 0);
}

// ---------- fused fp32 -> bf16 convert (x, wq, wk, wv; dst contiguous in ws) ----------
// wo is converted inside attn_k's prologue (hides in its latency-bound window).
__global__ __launch_bounds__(256) void cvt_all(const float* __restrict__ x,
                                               const float* __restrict__ wq,
                                               const float* __restrict__ wk,
                                               const float* __restrict__ wv,
                                               __bf16* __restrict__ dst) {
  int i = blockIdx.x * 256 + threadIdx.x;  // float4-chunk index, total 8,388,608
  const float* s;
  int j = i;
  if (j < 2097152) s = x;
  else if ((j -= 2097152) < 4194304) s = wq;
  else if ((j -= 4194304) < 1048576) s = wk;
  else { j -= 1048576; s = wv; }
  float4 v = ((const float4*)s)[j];
  bf16_4 o = { (__bf16)v.x, (__bf16)v.y, (__bf16)v.z, (__bf16)v.w };
  ((bf16_4*)dst)[i] = o;
}

// ---------- fused QKV GEMM (m97 128x128, BK=32) + fused RoPE epilogue ----------
__global__ __launch_bounds__(256) void gemm_qkv(const __bf16* __restrict__ xb,
                                                const __bf16* __restrict__ wqb,
                                                const __bf16* __restrict__ wkb,
                                                const __bf16* __restrict__ wvb,
                                                const float* __restrict__ cosT,
                                                const float* __restrict__ sinT,
                                                __bf16* __restrict__ Qb,
                                                __bf16* __restrict__ Kb,
                                                __bf16* __restrict__ Vt) {
  __shared__ __bf16 As[128 * 32];
  __shared__ __bf16 Bs[128 * 32];
  const int nb = blockIdx.x, mb = blockIdx.y;
  const __bf16* W; int wrow0;
  if (nb < 32)      { W = wqb; wrow0 = nb * 128; }
  else if (nb < 40) { W = wkb; wrow0 = (nb - 32) * 128; }
  else              { W = wvb; wrow0 = (nb - 40) * 128; }
  const int tid = threadIdx.x, lane = tid & 63, wv = tid >> 6;
  const int wm = wv >> 1, wn = wv & 1;
  const int srow = lane >> 2, scol = (lane & 3) * 8;

  const __bf16* Ag0 = xb + (size_t)(mb * 128 + 2 * wv * 16 + srow) * D_ + scol;
  const __bf16* Bg0 = W  + (size_t)(wrow0 + 2 * wv * 16 + srow) * D_ + scol;
  __bf16* Al = As + 2 * wv * 512;
  __bf16* Bl = Bs + 2 * wv * 512;

  const f32x4 zv = {0.f, 0.f, 0.f, 0.f};
  f32x4 acc[4][4];
#pragma unroll
  for (int i = 0; i < 4; ++i)
#pragma unroll
    for (int j = 0; j < 4; ++j) acc[i][j] = zv;

  for (int k0 = 0; k0 < D_; k0 += 32) {
    gload_lds16(Ag0 + k0, Al);
    gload_lds16(Ag0 + (size_t)16 * D_ + k0, Al + 512);
    gload_lds16(Bg0 + k0, Bl);
    gload_lds16(Bg0 + (size_t)16 * D_ + k0, Bl + 512);
    __syncthreads();
    bf16_8 af[4], bfr[4];
#pragma unroll
    for (int i = 0; i < 4; ++i)
      af[i] = *(const bf16_8*)&As[(wm * 64 + i * 16 + (lane & 15)) * 32 + (lane >> 4) * 8];
#pragma unroll
    for (int j = 0; j < 4; ++j)
      bfr[j] = *(const bf16_8*)&Bs[(wn * 64 + j * 16 + (lane & 15)) * 32 + (lane >> 4) * 8];
#pragma unroll
    for (int i = 0; i < 4; ++i)
#pragma unroll
      for (int j = 0; j < 4; ++j)
        acc[i][j] = __builtin_amdgcn_mfma_f32_16x16x32_bf16(af[i], bfr[j], acc[i][j], 0, 0, 0);
    __syncthreads();
  }

  // epilogue with fused RoPE for Q and K
#pragma unroll
  for (int i = 0; i < 4; ++i) {
    int row0 = mb * 128 + wm * 64 + i * 16 + (lane >> 4) * 4;
#pragma unroll
    for (int j = 0; j < 4; ++j) {
      int cl = wn * 64 + j * 16 + (lane & 15);
      if (nb < 40) {
        int f = cl >> 1;
        float sgn = (cl & 1) ? 1.f : -1.f;
        f32x4 v = acc[i][j];
        float o[4];
#pragma unroll
        for (int r = 0; r < 4; ++r) {
          float p = __shfl_xor(v[r], 1);  // partner column cl^1
          float c = cosT[(size_t)(row0 + r) * 64 + f];
          float s = sinT[(size_t)(row0 + r) * 64 + f];
          o[r] = v[r] * c + sgn * p * s;
        }
        if (nb < 32) {
          int colg = nb * 128 + cl;
#pragma unroll
          for (int r = 0; r < 4; ++r)
            Qb[(size_t)(row0 + r) * D_ + colg] = (__bf16)o[r];
        } else {
          int colg = (nb - 32) * 128 + cl;
#pragma unroll
          for (int r = 0; r < 4; ++r)
            Kb[(size_t)(row0 + r) * 1024 + colg] = (__bf16)o[r];
        }
      } else {
        int colg = (nb - 40) * 128 + cl;
        bf16_4 pv = { (__bf16)acc[i][j][0], (__bf16)acc[i][j][1],
                      (__bf16)acc[i][j][2], (__bf16)acc[i][j][3] };
        *(bf16_4*)&Vt[(size_t)colg * S_ + row0] = pv;  // transposed store
      }
    }
  }
}

// ---------- output-projection GEMM: out(fp32) = Ob @ wo^T (m97 128x128) ----------
__global__ __launch_bounds__(256) void gemm_out(const __bf16* __restrict__ Ob,
                                                const __bf16* __restrict__ wob,
                                                float* __restrict__ Of) {
  __shared__ __bf16 As[128 * 32];
  __shared__ __bf16 Bs[128 * 32];
  const int nb = blockIdx.x, mb = blockIdx.y;
  const int tid = threadIdx.x, lane = tid & 63, wv = tid >> 6;
  const int wm = wv >> 1, wn = wv & 1;
  const int srow = lane >> 2, scol = (lane & 3) * 8;

  const __bf16* Ag0 = Ob  + (size_t)(mb * 128 + 2 * wv * 16 + srow) * D_ + scol;
  const __bf16* Bg0 = wob + (size_t)(nb * 128 + 2 * wv * 16 + srow) * D_ + scol;
  __bf16* Al = As + 2 * wv * 512;
  __bf16* Bl = Bs + 2 * wv * 512;

  const f32x4 zv = {0.f, 0.f, 0.f, 0.f};
  f32x4 acc[4][4];
#pragma unroll
  for (int i = 0; i < 4; ++i)
#pragma unroll
    for (int j = 0; j < 4; ++j) acc[i][j] = zv;

  for (int k0 = 0; k0 < D_; k0 += 32) {
    gload_lds16(Ag0 + k0, Al);
    gload_lds16(Ag0 + (size_t)16 * D_ + k0, Al + 512);
    gload_lds16(Bg0 + k0, Bl);
    gload_lds16(Bg0 + (size_t)16 * D_ + k0, Bl + 512);
    __syncthreads();
    bf16_8 af[4], bfr[4];
#pragma unroll
    for (int i = 0; i < 4; ++i)
      af[i] = *(const bf16_8*)&As[(wm * 64 + i * 16 + (lane & 15)) * 32 + (lane >> 4) * 8];
#pragma unroll
    for (int j = 0; j < 4; ++j)
      bfr[j] = *(const bf16_8*)&Bs[(wn * 64 + j * 16 + (lane & 15)) * 32 + (lane >> 4) * 8];
#pragma unroll
    for (int i = 0; i < 4; ++i)
#pragma unroll
      for (int j = 0; j < 4; ++j)
        acc[i][j] = __builtin_amdgcn_mfma_f32_16x16x32_bf16(af[i], bfr[j], acc[i][j], 0, 0, 0);
    __syncthreads();
  }

#pragma unroll
  for (int i = 0; i < 4; ++i) {
    int row0 = mb * 128 + wm * 64 + i * 16 + (lane >> 4) * 4;
#pragma unroll
    for (int j = 0; j < 4; ++j) {
      int colg = nb * 128 + wn * 64 + j * 16 + (lane & 15);
#pragma unroll
      for (int r = 0; r < 4; ++r)
        Of[(size_t)(row0 + r) * D_ + colg] = acc[i][j][r];
    }
  }
}

// ---------- flash attention (causal, GQA), parallel-pair, SWAPPED QK^T, KVB=64 ----------
// 512 blocks (XCD-aligned kvh = bid%8), 512 threads = 8 waves: waves 0-3 -> hi tile,
// waves 4-7 -> lo tile. Balanced x remap: second dispatch wave gets complementary x
// so per-CU iteration sum is constant (49). Prologue converts wo -> wob (hidden).
#define COMPUTE_TILE(ACC, MR, LR, AQ, QB0, DOMASK, KSB, VSB)                       \
  {                                                                                \
    f32x4 sfr_[4];                                                                 \
    __builtin_amdgcn_s_setprio(1);                                                 \
    _Pragma("unroll")                                                              \
    for (int nf = 0; nf < 4; ++nf) {                                               \
      f32x4 c_ = zv;                                                               \
      _Pragma("unroll")                                                            \
      for (int ks = 0; ks < 4; ++ks) {                                             \
        int n_ = nf * 16 + (lane & 15);                                            \
        int bo_ = (n_ * 256 + (ks * 32 + (lane >> 4) * 8) * 2) ^ ((n_ & 7) << 4);  \
        bf16_8 bk_ = *(const bf16_8*)((char*)(KSB) + bo_);                         \
        c_ = __builtin_amdgcn_mfma_f32_16x16x32_bf16(bk_, AQ[ks], c_, 0, 0, 0);    \
      }                                                                            \
      sfr_[nf] = c_;                                                               \
    }                                                                              \
    __builtin_amdgcn_s_setprio(0);                                                 \
    const int myq_ = (QB0) + w4 * 16 + (lane & 15);                                \
    float pmn_[4];                                                                 \
    _Pragma("unroll")                                                              \
    for (int nf = 0; nf < 4; ++nf) {                                               \
      float t_ = -3e38f;                                                           \
      _Pragma("unroll")                                                            \
      for (int r = 0; r < 4; ++r) {                                                \
        int kcol_ = kb * 64 + nf * 16 + (lane >> 4) * 4 + r;                       \
        float v_ = sfr_[nf][r];                                                    \
        if ((DOMASK) && kcol_ > myq_) v_ = -1e9f;                                  \
        sfr_[nf][r] = v_;                                                          \
        t_ = fmaxf(t_, v_);                                                        \
      }                                                                            \
      pmn_[nf] = t_;                                                               \
    }                                                                              \
    float pm_ = fmaxf(fmaxf(pmn_[0], pmn_[1]), fmaxf(pmn_[2], pmn_[3]));           \
    pm_ = fmaxf(pm_, __shfl_xor(pm_, 16));                                         \
    pm_ = fmaxf(pm_, __shfl_xor(pm_, 32));                                         \
    if (!__all(pm_ <= MR + 8.f)) {                                                 \
      float mn_ = fmaxf(MR, pm_);                                                  \
      float rs_ = __expf(MR - mn_);                                                \
      MR = mn_;                                                                    \
      LR *= rs_;                                                                   \
      float rsb_[4];                                                               \
      _Pragma("unroll")                                                            \
      for (int r = 0; r < 4; ++r)                                                  \
        rsb_[r] = __shfl(rs_, (lane & 48) | ((lane >> 4) * 4 + r));                \
      _Pragma("unroll")                                                            \
      for (int d = 0; d < 8; ++d)                                                  \
        _Pragma("unroll")                                                          \
        for (int r = 0; r < 4; ++r) ACC[d][r] *= rsb_[r];                          \
    }                                                                              \
    float psn_[4];                                                                 \
    _Pragma("unroll")                                                              \
    for (int nf = 0; nf < 4; ++nf) {                                               \
      bf16_4 pk_;                                                                  \
      float t_ = 0.f;                                                              \
      _Pragma("unroll")                                                            \
      for (int r = 0; r < 4; ++r) {                                                \
        float p_ = __expf(sfr_[nf][r] - MR);                                       \
        t_ += p_;                                                                  \
        pk_[r] = (__bf16)p_;                                                       \
      }                                                                            \
      psn_[nf] = t_;                                                               \
      int bo_ = ((lane & 15) * 128 + nf * 32 + (lane >> 4) * 8) ^                  \
                (((lane & 15) & 7) << 4);                                          \
      *(bf16_4*)((char*)(&Ps[wid][0]) + bo_) = pk_;                                \
    }                                                                              \
    float ps_ = (psn_[0] + psn_[1]) + (psn_[2] + psn_[3]);                         \
    ps_ += __shfl_xor(ps_, 16);                                                    \
    ps_ += __shfl_xor(ps_, 32);                                                    \
    LR += ps_;                                                                     \
    bf16_8 ap_[2];                                                                 \
    _Pragma("unroll")                                                              \
    for (int ks = 0; ks < 2; ++ks) {                                               \
      int bo_ = ((lane & 15) * 128 + (ks * 32 + (lane >> 4) * 8) * 2) ^            \
                (((lane & 15) & 7) << 4);                                          \
      ap_[ks] = *(const bf16_8*)((char*)(&Ps[wid][0]) + bo_);                      \
    }                                                                              \
    __builtin_amdgcn_s_setprio(1);                                                 \
    _Pragma("unroll")                                                              \
    for (int d = 0; d < 8; ++d) {                                                  \
      _Pragma("unroll")                                                            \
      for (int ks = 0; ks < 2; ++ks) {                                             \
        int dr_ = d * 16 + (lane & 15);                                            \
        int bo_ = (dr_ * 128 + (ks * 32 + (lane >> 4) * 8) * 2) ^ ((dr_ & 7) << 4);\
        bf16_8 bv_ = *(const bf16_8*)((char*)(VSB) + bo_);                         \
        ACC[d] = __builtin_amdgcn_mfma_f32_16x16x32_bf16(ap_[ks], bv_, ACC[d], 0, 0, 0); \
      }                                                                            \
    }                                                                              \
    __builtin_amdgcn_s_setprio(0);                                                 \
  }

__global__ __launch_bounds__(512, 4) void attn_k(const __bf16* __restrict__ Qb,
                                                 const __bf16* __restrict__ Kb,
                                                 const __bf16* __restrict__ Vt,
                                                 const float* __restrict__ wo,
                                                 __bf16* __restrict__ wob,
                                                 __bf16* __restrict__ Ob) {
  __shared__ __bf16 Ks[2][64 * 128];   // K[pos][d], row 256B, phys chunk = logical^(row&7)
  __shared__ __bf16 Vs[2][128 * 64];   // V^T[d][pos], row 128B, same swizzle convention
  __shared__ __bf16 Ps[8][16 * 64];    // per-wave P[q][k], row 128B, swizzled

  // ---- prologue: convert wo (fp32) -> wob (bf16), 16 chunks/thread exactly ----
  {
    const float4* src = (const float4*)wo;
    bf16_4* dst = (bf16_4*)wob;
    int t0 = blockIdx.x * 512 + threadIdx.x;
#pragma unroll
    for (int u = 0; u < 16; ++u) {
      int idx = t0 + u * 262144;
      float4 v = src[idx];
      bf16_4 o = { (__bf16)v.x, (__bf16)v.y, (__bf16)v.z, (__bf16)v.w };
      dst[idx] = o;
    }
  }

  const int bid = blockIdx.x;
  const int kvh = bid & 7;             // XCD-aligned: each XCD serves one KV head
  const int hsel = (bid >> 3) & 3;
  const int h = kvh * 4 + hsel;
  const int xraw = (bid >> 5) & 7;
  const int x = (bid >> 8) ? (15 - xraw) : xraw;  // balanced pairing across dispatch waves
  const int qlo = x, qhi = 31 - x;
  const int tid = threadIdx.x, lane = tid & 63, wid = tid >> 6;
  const int w4 = wid & 3;              // row-group within tile
  const int qt = (wid < 4) ? qhi : qlo;  // waves 0-3: hi tile, 4-7: lo tile

  const float sc = 0.08838834764831845f;  // 1/sqrt(128)

  // Q fragments for this wave's tile, pre-scaled by 1/sqrt(d)
  bf16_8 aq[4];
#pragma unroll
  for (int ks = 0; ks < 4; ++ks) {
    int rr = qt * 64 + w4 * 16 + (lane & 15);
    int cc = h * 128 + ks * 32 + (lane >> 4) * 8;
    bf16_8 t = *(const bf16_8*)&Qb[(size_t)rr * D_ + cc];
#pragma unroll
    for (int e = 0; e < 8; ++e) aq[ks][e] = (__bf16)((float)t[e] * sc);
  }

  const f32x4 zv = {0.f, 0.f, 0.f, 0.f};
  f32x4 acc[8];
#pragma unroll
  for (int d = 0; d < 8; ++d) acc[d] = zv;
  float mr = -3e38f, lr = 0.f;

  // 1024 K-chunks + 1024 V-chunks over 512 threads: 2+2 gload_lds16 each.
#define KSTAGE(BUF, KB)                                                            \
  {                                                                                \
    _Pragma("unroll")                                                              \
    for (int u = 0; u < 2; ++u) {                                                  \
      int chunk = (u * 8 + wid) * 64 + lane;                                       \
      int row = chunk >> 4, p8 = chunk & 15;                                       \
      gload_lds16(&Kb[(size_t)((KB) * 64 + row) * 1024 + kvh * 128 + (p8 ^ (row & 7)) * 8], \
                  &Ks[BUF][(u * 8 + wid) * 512]);                                  \
    }                                                                              \
    _Pragma("unroll")                                                              \
    for (int u = 0; u < 2; ++u) {                                                  \
      int chunk = (u * 8 + wid) * 64 + lane;                                       \
      int vr = chunk >> 3, p8 = chunk & 7;                                         \
      gload_lds16(&Vt[(size_t)(kvh * 128 + vr) * S_ + (KB) * 64 + (p8 ^ (vr & 7)) * 8], \
                  &Vs[BUF][(u * 8 + wid) * 512]);                                  \
    }                                                                              \
  }

  KSTAGE(0, 0);
  asm volatile("s_waitcnt vmcnt(0)" ::: "memory");
  __syncthreads();

  for (int kb = 0; kb <= qhi; ++kb) {
    const int cur = kb & 1;
    if (kb < qhi) KSTAGE(cur ^ 1, kb + 1);  // async into idle buffer
    const __bf16* ksb = &Ks[cur][0];
    const __bf16* vsb = &Vs[cur][0];
    if (kb <= qt) COMPUTE_TILE(acc, mr, lr, aq, qt * 64, (kb == qt), ksb, vsb);
    if (kb < qhi) {
      asm volatile("s_waitcnt vmcnt(0)" ::: "memory");
      __syncthreads();
    }
  }

  // normalize + store (l lives at lane q = lane&15 -> shuffle per row)
  float inv[4];
#pragma unroll
  for (int r = 0; r < 4; ++r)
    inv[r] = 1.0f / __shfl(lr, (lane & 48) | ((lane >> 4) * 4 + r));
#pragma unroll
  for (int d = 0; d < 8; ++d) {
#pragma unroll
    for (int r = 0; r < 4; ++r) {
      size_t row = (size_t)(qt * 64 + w4 * 16 + (lane >> 4) * 4 + r);
      Ob[row * D_ + h * 128 + d * 16 + (lane & 15)] = (__bf16)(acc[d][r] * inv[r]);
    }
  }
}

// ---------- launch ----------
extern "C" void kernel_launch(void* const* d_in, const int* in_sizes, int n_in,
                              void* d_out, int out_size, void* d_ws, size_t ws_size,
                              hipStream_t stream) {
  const float* x    = (const float*)d_in[0];
  const float* wq   = (const float*)d_in[1];
  const float* wk   = (const float*)d_in[2];
  const float* wv   = (const float*)d_in[3];
  const float* wo   = (const float*)d_in[4];
  const float* cosT = (const float*)d_in[5];
  const float* sinT = (const float*)d_in[6];
  float* out = (float*)d_out;
  char* ws = (char*)d_ws;

  __bf16* xb  = (__bf16*)(ws + 0);            // 2048x4096; later reused as Ob
  __bf16* wqb = (__bf16*)(ws + 16777216);     // 4096x4096
  __bf16* wkb = (__bf16*)(ws + 50331648);     // 1024x4096
  __bf16* wvb = (__bf16*)(ws + 58720256);     // 1024x4096
  __bf16* wob = (__bf16*)(ws + 67108864);     // 4096x4096 (converted in attn_k)
  __bf16* Qb  = (__bf16*)(ws + 100663296);    // 2048x4096
  __bf16* Kb  = (__bf16*)(ws + 117440512);    // 2048x1024
  __bf16* Vt  = (__bf16*)(ws + 121634816);    // 1024x2048 (V transposed)
  __bf16* Ob  = xb;                           // alias: x consumed before attention writes

  // fused fp32 -> bf16 for x, wq, wk, wv (dst = xb..wvb contiguous)
  cvt_all<<<32768, 256, 0, stream>>>(x, wq, wk, wv, xb);

  // fused QKV projection + RoPE, m97 128x128 BK=32 (V stored transposed)
  gemm_qkv<<<dim3(48, 16), 256, 0, stream>>>(xb, wqb, wkb, wvb, cosT, sinT, Qb, Kb, Vt);

  // causal GQA flash attention (parallel-pair, balanced x, XCD-aligned KV heads)
  // + hidden wo->wob conversion in prologue
  attn_k<<<512, 512, 0, stream>>>(Qb, Kb, Vt, wo, wob, Ob);

  // output projection -> fp32 (m97 128x128 BK=32)
  gemm_out<<<dim3(32, 16), 256, 0, stream>>>(Ob, wob, out);
}